// Round 5
// baseline (362.526 us; speedup 1.0000x reference)
//
#include <hip/hip_runtime.h>

// LSTM RNN: B=2048, L=256 (257 scan steps), F=64, H=32, K=2.
// R6 (resubmit; previous bench failed on container infra, no GPU verdict):
//     BARRIER-FREE main loop. 256 wgs x 512 threads (8 waves); each wave owns
//     ONE batch (A rows dup x16 -> all rows = h of that batch). Wave computes
//     all 256 gate cols itself: 16 slots x K-chain(2) = 32 MFMA + 2 logit MFMA.
//     h-exchange is intra-wave via a per-wave 64-entry LDS buffer (same-wave DS
//     ops are in-order -> no __syncthreads in the loop). Lane l owns f=l; its 4
//     gate values sit in slot gt*4+q, col n2 -> 3-cndmask static select.
//     2 waves/SIMD (launch_bounds 512,2) hide each other's LDS/chain latency.
//     Softplus off the serial path: signed logit diff stashed to LDS per step,
//     vectorized softplus+wave-reduce in barrier-free epilogue.
//     Gate cols pre-scaled by -L2E (i,f,o) / -2*L2E (g); cs = -2*L2E*c.

typedef __attribute__((ext_vector_type(8))) short bf16x8;
typedef __attribute__((ext_vector_type(4))) float f32x4;

#define L2E 1.44269504088896340736f
#define LN2 0.69314718055994530942f

__device__ __forceinline__ short f2bf(float x) {
    unsigned u = __builtin_bit_cast(unsigned, x);
    unsigned r = (u + 0x7FFFu + ((u >> 16) & 1u)) >> 16;
    return (short)r;
}

__global__ __launch_bounds__(512, 2) void lstm_kernel(
    const int* __restrict__ s, const float* __restrict__ g,
    const float* __restrict__ W_emb, const float* __restrict__ b_emb,
    const float* __restrict__ W_g1, const float* __restrict__ b_g1,
    const float* __restrict__ W_g2, const float* __restrict__ b_g2,
    const float* __restrict__ W_gh, const float* __restrict__ b_gh,
    const float* __restrict__ W_gc, const float* __restrict__ b_gc,
    const float* __restrict__ Wi, const float* __restrict__ Wh,
    const float* __restrict__ b_lstm, const float* __restrict__ W_amp,
    const float* __restrict__ b_amp, float* __restrict__ out)
{
    __shared__ float Bx[35 * 256];              // 0-31: W_g2@Wi; 32-33: W_emb@Wi; 34: const (pre-scaled)
    __shared__ unsigned char sp_l[260];         // packed tokens: bit b of sp_l[t] = s_pad[b][t], 8 batches
    __shared__ __align__(16) short Hl[8][2][64];// per-wave h double buffer (f = index)
    __shared__ __align__(16) float dLb[8][256]; // per-wave signed logit diffs

    const int tid = threadIdx.x;
    const int w   = tid >> 6;     // wave 0..7 == batch within wg
    const int l   = tid & 63;     // lane; owns state f = l
    const int n2  = l & 15;       // MFMA col
    const int q   = l >> 4;       // MFMA k-quad
    const int wgb = blockIdx.x * 8;
    const int bat = wgb + w;

    // ---------- Setup (first 256 threads): folded B rows into LDS, pre-scaled ----------
    if (tid < 256) {
        const int n = tid;
        // cols [0,64)=i, [64,128)=f: -L2E; [128,192)=g: -2*L2E; [192,256)=o: -L2E
        const float sc = (n >= 128 && n < 192) ? (-2.0f * L2E) : (-L2E);
        float acc[35];
        #pragma unroll
        for (int i = 0; i < 35; ++i) acc[i] = 0.f;
        for (int f = 0; f < 64; ++f) {
            float wi = Wi[f * 256 + n] * sc;
            #pragma unroll
            for (int k = 0; k < 32; ++k) acc[k] += W_g2[k * 64 + f] * wi;  // uniform
            acc[32] += W_emb[f] * wi;
            acc[33] += W_emb[64 + f] * wi;
            acc[34] += (b_emb[f] + b_g2[f]) * wi;
        }
        acc[34] += b_lstm[n] * sc;
        #pragma unroll
        for (int i = 0; i < 35; ++i) Bx[i * 256 + n] = acc[i];
        // token staging: sp_l[t+1] bits = s[:, t] for 8 batch rows
        unsigned v = 0;
        #pragma unroll
        for (int b = 0; b < 8; ++b)
            v |= (unsigned)(s[(wgb + b) * 256 + n] & 1) << b;
        sp_l[n + 1] = (unsigned char)v;
        if (n == 0) sp_l[0] = 0;
    }
    __syncthreads();

    // ---------- static fragments: full Wh (all 16 col-groups), pre-scaled ----------
    bf16x8 Bf[16][2];   // 128 VGPRs
    #pragma unroll
    for (int m = 0; m < 16; ++m) {
        const int n = m * 16 + n2;
        const float scg = (m >= 8 && m < 12) ? (-2.0f * L2E) : (-L2E);
        #pragma unroll
        for (int kf = 0; kf < 2; ++kf)
            #pragma unroll
            for (int j = 0; j < 8; ++j)
                Bf[m][kf][j] = f2bf(Wh[(kf * 32 + q * 8 + j) * 256 + n] * scg);
    }

    // per-lane gate base consts at col n = gt*64 + l (f32 dot, full precision)
    const float g_b = g[bat];
    float y0[4], Ds[4];
    {
        float atv[32];
        #pragma unroll
        for (int k = 0; k < 32; ++k)
            atv[k] = tanhf(g_b * W_g1[k] + b_g1[k]);
        #pragma unroll
        for (int gt = 0; gt < 4; ++gt) {
            const int n = gt * 64 + l;
            float a = Bx[32 * 256 + n] + Bx[34 * 256 + n];
            #pragma unroll
            for (int k = 0; k < 32; ++k)
                a += atv[k] * Bx[k * 256 + n];
            y0[gt] = a;
            Ds[gt] = Bx[33 * 256 + n] - Bx[32 * 256 + n];
        }
    }

    // logit DIFF column frags (col 0 = W_amp[:,1]-W_amp[:,0]; others 0) — NOT scaled
    bf16x8 BLd0, BLd1;
    f32x4 CL0;
    {
        #pragma unroll
        for (int j = 0; j < 8; ++j) {
            int k = q * 8 + j;
            BLd0[j] = (n2 == 0) ? f2bf(W_amp[k * 2 + 1] - W_amp[k * 2]) : (short)0;
            BLd1[j] = (n2 == 0) ? f2bf(W_amp[(k + 32) * 2 + 1] - W_amp[(k + 32) * 2]) : (short)0;
        }
        float bd = (n2 == 0) ? (b_amp[1] - b_amp[0]) : 0.f;
        CL0[0] = bd; CL0[1] = bd; CL0[2] = bd; CL0[3] = bd;
    }

    // ---------- state init (cs = -2*L2E*c) ----------
    float cs = (-2.0f * L2E) * (g_b * W_gc[l] + b_gc[l]);
    Hl[w][0][l] = f2bf(g_b * W_gh[l] + b_gh[l]);
    // no barrier: Hl[w] is private to this wave; same-wave DS ops are in-order

    // ---------- main recurrence (barrier-free) ----------
    const bool qb0 = (q & 1) != 0;
    const bool qb1 = (q & 2) != 0;

    auto step = [&](int t, int rb, bool doLogit) {
        bf16x8 a0 = *(const bf16x8*)&Hl[w][rb][q * 8];        // f = q*8..+8   (K 0..31)
        bf16x8 a1 = *(const bf16x8*)&Hl[w][rb][32 + q * 8];   // f = 32+q*8..  (K 32..63)
        const unsigned bit = ((unsigned)sp_l[t] >> w) & 1u;   // token s_pad[t], wave-uniform
        const float fb = (float)bit;
        const f32x4 z4 = {0.f, 0.f, 0.f, 0.f};

        float y[4];
        #pragma unroll
        for (int gt = 0; gt < 4; ++gt) {
            f32x4 c0 = __builtin_amdgcn_mfma_f32_16x16x32_bf16(a1, Bf[4 * gt + 0][1], z4, 0, 0, 0);
            c0 = __builtin_amdgcn_mfma_f32_16x16x32_bf16(a0, Bf[4 * gt + 0][0], c0, 0, 0, 0);
            f32x4 c1 = __builtin_amdgcn_mfma_f32_16x16x32_bf16(a1, Bf[4 * gt + 1][1], z4, 0, 0, 0);
            c1 = __builtin_amdgcn_mfma_f32_16x16x32_bf16(a0, Bf[4 * gt + 1][0], c1, 0, 0, 0);
            f32x4 c2 = __builtin_amdgcn_mfma_f32_16x16x32_bf16(a1, Bf[4 * gt + 2][1], z4, 0, 0, 0);
            c2 = __builtin_amdgcn_mfma_f32_16x16x32_bf16(a0, Bf[4 * gt + 2][0], c2, 0, 0, 0);
            f32x4 c3 = __builtin_amdgcn_mfma_f32_16x16x32_bf16(a1, Bf[4 * gt + 3][1], z4, 0, 0, 0);
            c3 = __builtin_amdgcn_mfma_f32_16x16x32_bf16(a0, Bf[4 * gt + 3][0], c3, 0, 0, 0);
            // lane's col n = gt*64 + l lives in slot gt*4+q, col n2 -> static select by q
            float s01 = qb0 ? c1[0] : c0[0];
            float s23 = qb0 ? c3[0] : c2[0];
            y[gt] = __builtin_fmaf(fb, Ds[gt], (qb1 ? s23 : s01) + y0[gt]);
        }

        if (doLogit) {
            f32x4 aL = __builtin_amdgcn_mfma_f32_16x16x32_bf16(a1, BLd1, CL0, 0, 0, 0);
            aL = __builtin_amdgcn_mfma_f32_16x16x32_bf16(a0, BLd0, aL, 0, 0, 0);
            float dL = bit ? -aL[0] : aL[0];        // l_other - l_token
            if (l == 0) dLb[w][t - 1] = dL;
        }

        // activations: y's are -L2E*z (i,f,o) and -2*L2E*z (g)
        float si = __builtin_amdgcn_rcpf(1.0f + __builtin_amdgcn_exp2f(y[0]));
        float sf = __builtin_amdgcn_rcpf(1.0f + __builtin_amdgcn_exp2f(y[1]));
        float rg = __builtin_amdgcn_rcpf(1.0f + __builtin_amdgcn_exp2f(y[2]));
        float so = __builtin_amdgcn_rcpf(1.0f + __builtin_amdgcn_exp2f(y[3]));
        float tgs = __builtin_fmaf(-4.0f * L2E, rg, 2.0f * L2E);   // -2*L2E*tanh(zg)
        cs = __builtin_fmaf(sf, cs, si * tgs);                      // cs' = -2*L2E*c'
        float r5 = __builtin_amdgcn_rcpf(1.0f + __builtin_amdgcn_exp2f(cs));
        float th = __builtin_fmaf(2.0f, r5, -1.0f);                 // tanh(c')
        float h  = so * th;
        unsigned hv;
        asm("v_cvt_pk_bf16_f32 %0, %1, %2" : "=v"(hv) : "v"(h), "v"(h));
        Hl[w][rb ^ 1][l] = (short)hv;
    };

    step(0, 0, false);
    for (int t = 1; t < 256; t += 2) {
        step(t, 1, true);
        step(t + 1, 0, true);
    }
    // loop covered t = 1..256 (logits for positions 0..255)

    // ---------- epilogue (per-wave, barrier-free): softplus + reduce ----------
    float accs = 0.f;
    {
        f32x4 v = *(const f32x4*)&dLb[w][l * 4];
        #pragma unroll
        for (int r = 0; r < 4; ++r)
            accs += __builtin_amdgcn_logf(1.0f + __builtin_amdgcn_exp2f(L2E * v[r]));
    }
    #pragma unroll
    for (int off = 1; off < 64; off <<= 1)
        accs += __shfl_xor(accs, off, 64);
    if (l == 0) out[bat] = -LN2 * accs;
}

extern "C" void kernel_launch(void* const* d_in, const int* in_sizes, int n_in,
                              void* d_out, int out_size, void* d_ws, size_t ws_size,
                              hipStream_t stream) {
    (void)in_sizes; (void)n_in; (void)out_size; (void)d_ws; (void)ws_size;
    const int*   s      = (const int*)d_in[0];
    const float* g      = (const float*)d_in[1];
    const float* W_emb  = (const float*)d_in[2];
    const float* b_emb  = (const float*)d_in[3];
    const float* W_g1   = (const float*)d_in[4];
    const float* b_g1   = (const float*)d_in[5];
    const float* W_g2   = (const float*)d_in[6];
    const float* b_g2   = (const float*)d_in[7];
    const float* W_gh   = (const float*)d_in[8];
    const float* b_gh   = (const float*)d_in[9];
    const float* W_gc   = (const float*)d_in[10];
    const float* b_gc   = (const float*)d_in[11];
    const float* Wi     = (const float*)d_in[12];
    const float* Wh     = (const float*)d_in[13];
    const float* b_lstm = (const float*)d_in[14];
    const float* W_amp  = (const float*)d_in[15];
    const float* b_amp  = (const float*)d_in[16];
    float* out = (float*)d_out;

    lstm_kernel<<<256, 512, 0, stream>>>(s, g, W_emb, b_emb, W_g1, b_g1, W_g2, b_g2,
                                         W_gh, b_gh, W_gc, b_gc, Wi, Wh, b_lstm,
                                         W_amp, b_amp, out);
}